// Round 1
// baseline (79.849 us; speedup 1.0000x reference)
//
#include <hip/hip_runtime.h>

#define EPS 1e-7f
#define LOG2E 1.44269504088896340736f

constexpr int SEGS  = 32;   // i-dimension split; partials = SEGS*M*8B = 2 MB in d_ws
constexpr int BLOCK = 256;

// Kernel 1: each thread owns one output j and a segment of the i-loop,
// accumulating partial (numerator, denominator) sums.
__global__ __launch_bounds__(BLOCK) void nw_partial(
    const float2* __restrict__ x,        // M x 2 query points
    const float2* __restrict__ inputs,   // N x 2 data points
    const float*  __restrict__ outputs,  // N
    const float*  __restrict__ bw,       // M
    float2*       __restrict__ partial,  // SEGS x M  (num, den)
    int N, int M)
{
    const int j   = blockIdx.x * BLOCK + threadIdx.x;
    const int seg = blockIdx.y;
    const int per = (N + SEGS - 1) / SEGS;
    const int i0  = seg * per;
    const int i1  = min(N, i0 + per);

    float x0 = 0.f, x1 = 0.f, k = 0.f;
    if (j < M) {
        float2 xj = x[j];
        x0 = xj.x;
        x1 = xj.y;
        float b = bw[j];
        k = -LOG2E / (2.0f * b * b);   // exp(-d2/(2b^2)) == exp2(d2 * k)
    }

    float num = 0.f, den = 0.f;
    #pragma unroll 8
    for (int i = i0; i < i1; ++i) {
        // i is block-uniform -> these become scalar (s_load) accesses
        float2 p  = inputs[i];
        float  oi = outputs[i];
        float dx = p.x - x0;
        float dy = p.y - x1;
        float d2 = fmaf(dx, dx, dy * dy);          // == max(a2+b2-2ab, 0) exactly
        float w  = __builtin_amdgcn_exp2f(d2 * k); // v_exp_f32
        num = fmaf(w, oi, num);
        den += w;
    }

    if (j < M) partial[seg * M + j] = make_float2(num, den);
}

// Kernel 2: reduce the SEGS partials per output and normalize.
__global__ __launch_bounds__(BLOCK) void nw_finalize(
    const float2* __restrict__ partial,
    float*        __restrict__ out,
    int M)
{
    const int j = blockIdx.x * BLOCK + threadIdx.x;
    if (j >= M) return;
    float num = 0.f, den = 0.f;
    #pragma unroll
    for (int s = 0; s < SEGS; ++s) {
        float2 p = partial[s * M + j];   // coalesced across j
        num += p.x;
        den += p.y;
    }
    out[j] = num / (den + EPS);
}

extern "C" void kernel_launch(void* const* d_in, const int* in_sizes, int n_in,
                              void* d_out, int out_size, void* d_ws, size_t ws_size,
                              hipStream_t stream) {
    // setup_inputs() dict order: x (M*2), inputs (N*2), outputs (N), bandwidth (M)
    const float2* x       = (const float2*)d_in[0];
    const float2* inputs  = (const float2*)d_in[1];
    const float*  outputs = (const float*) d_in[2];
    const float*  bwv     = (const float*) d_in[3];
    const int N = in_sizes[2];   // outputs element count
    const int M = in_sizes[3];   // bandwidth element count
    float*        out     = (float*)d_out;
    float2*       partial = (float2*)d_ws; // SEGS * M * sizeof(float2) = 2 MB

    dim3 grid1((M + BLOCK - 1) / BLOCK, SEGS);
    nw_partial<<<grid1, BLOCK, 0, stream>>>(x, inputs, outputs, bwv, partial, N, M);

    dim3 grid2((M + BLOCK - 1) / BLOCK);
    nw_finalize<<<grid2, BLOCK, 0, stream>>>(partial, out, M);
}

// Round 2
// 79.392 us; speedup vs baseline: 1.0058x; 1.0058x over previous
//
#include <hip/hip_runtime.h>

#define EPS 1e-7f
#define LOG2E 1.44269504088896340736f

constexpr int SEGS  = 64;   // i-split: 2048 blocks -> 8 blocks/CU -> max occupancy
constexpr int BLOCK = 256;

// Kernel 0: pack (px, py, px^2+py^2, outputs[i]) into one float4 per data point
// so the main loop does a single uniform s_load per pair and 3 FMAs.
__global__ __launch_bounds__(BLOCK) void nw_pack(
    const float2* __restrict__ inputs,
    const float*  __restrict__ outputs,
    float4*       __restrict__ packed,
    int N)
{
    int i = blockIdx.x * BLOCK + threadIdx.x;
    if (i < N) {
        float2 p = inputs[i];
        packed[i] = make_float4(p.x, p.y, fmaf(p.x, p.x, p.y * p.y), outputs[i]);
    }
}

// Kernel 1: each thread owns one output j and a segment of the i-loop.
// exp(-d2/(2b^2)) = exp2(c0*s_i + c1*px + c2*py + c3) with per-thread c0..c3:
//   k  = -log2(e)/(2 b^2)
//   c0 = k, c1 = -2k*x0, c2 = -2k*x1, c3 = k*(x0^2+x1^2)
__global__ __launch_bounds__(BLOCK) void nw_partial(
    const float4* __restrict__ packed,   // N x (px,py,s,o) -- uniform loads
    const float2* __restrict__ x,        // M x 2 query points
    const float*  __restrict__ bw,       // M
    float2*       __restrict__ partial,  // SEGS x M  (num, den)
    int N, int M)
{
    const int j   = blockIdx.x * BLOCK + threadIdx.x;
    const int seg = blockIdx.y;
    const int per = (N + SEGS - 1) / SEGS;
    const int i0  = seg * per;
    const int i1  = min(N, i0 + per);

    float c0 = 0.f, c1 = 0.f, c2 = 0.f, c3 = 0.f;
    if (j < M) {
        float2 xj = x[j];
        float  b  = bw[j];
        float  k  = -LOG2E / (2.0f * b * b);
        c0 = k;
        c1 = -2.0f * k * xj.x;
        c2 = -2.0f * k * xj.y;
        c3 = k * fmaf(xj.x, xj.x, xj.y * xj.y);
    }

    // dual accumulators: 2 pairs per iteration (v_pk_fma_f32 opportunity)
    float num0 = 0.f, num1 = 0.f, den0 = 0.f, den1 = 0.f;
    int i = i0;
    #pragma unroll 4
    for (; i + 1 < i1; i += 2) {
        float4 pa = packed[i];       // uniform address -> s_load
        float4 pb = packed[i + 1];
        float ta = fmaf(c0, pa.z, fmaf(c1, pa.x, fmaf(c2, pa.y, c3)));
        float tb = fmaf(c0, pb.z, fmaf(c1, pb.x, fmaf(c2, pb.y, c3)));
        float wa = __builtin_amdgcn_exp2f(ta);
        float wb = __builtin_amdgcn_exp2f(tb);
        num0 = fmaf(wa, pa.w, num0);
        num1 = fmaf(wb, pb.w, num1);
        den0 += wa;
        den1 += wb;
    }
    if (i < i1) {  // odd tail
        float4 pa = packed[i];
        float ta = fmaf(c0, pa.z, fmaf(c1, pa.x, fmaf(c2, pa.y, c3)));
        float wa = __builtin_amdgcn_exp2f(ta);
        num0 = fmaf(wa, pa.w, num0);
        den0 += wa;
    }

    if (j < M) partial[seg * M + j] = make_float2(num0 + num1, den0 + den1);
}

// Kernel 2: reduce the SEGS partials per output and normalize.
__global__ __launch_bounds__(BLOCK) void nw_finalize(
    const float2* __restrict__ partial,
    float*        __restrict__ out,
    int M)
{
    const int j = blockIdx.x * BLOCK + threadIdx.x;
    if (j >= M) return;
    float num = 0.f, den = 0.f;
    #pragma unroll
    for (int s = 0; s < SEGS; ++s) {
        float2 p = partial[s * M + j];   // coalesced across j
        num += p.x;
        den += p.y;
    }
    out[j] = num / (den + EPS);
}

extern "C" void kernel_launch(void* const* d_in, const int* in_sizes, int n_in,
                              void* d_out, int out_size, void* d_ws, size_t ws_size,
                              hipStream_t stream) {
    // setup_inputs() dict order: x (M*2), inputs (N*2), outputs (N), bandwidth (M)
    const float2* x       = (const float2*)d_in[0];
    const float2* inputs  = (const float2*)d_in[1];
    const float*  outputs = (const float*) d_in[2];
    const float*  bwv     = (const float*) d_in[3];
    const int N = in_sizes[2];   // outputs element count
    const int M = in_sizes[3];   // bandwidth element count
    float*        out     = (float*)d_out;

    // ws layout: [0, SEGS*M*8) partials ; [4MB, +N*16) packed
    float2* partial = (float2*)d_ws;
    float4* packed  = (float4*)((char*)d_ws + (size_t)SEGS * M * sizeof(float2));

    nw_pack<<<dim3((N + BLOCK - 1) / BLOCK), BLOCK, 0, stream>>>(inputs, outputs, packed, N);

    dim3 grid1((M + BLOCK - 1) / BLOCK, SEGS);
    nw_partial<<<grid1, BLOCK, 0, stream>>>(packed, x, bwv, partial, N, M);

    nw_finalize<<<dim3((M + BLOCK - 1) / BLOCK), BLOCK, 0, stream>>>(partial, out, M);
}